// Round 7
// baseline (613.173 us; speedup 1.0000x reference)
//
#include <hip/hip_runtime.h>

// ---------------------------------------------------------------------------
// PolaLinearAttention on MI355X (gfx950), f16 MFMA pipeline.
// B=8 N=4096 C=768 Hn=12 hd=64. All matmuls via v_mfma_f32_16x16x32_f16.
// Blocked operand layout for MFMA operands (128-row tiles):
//   off(row, k) = (row/128)*(128*K) + (k/8)*1024 + (row%128)*8 + (k%8)
// q^p / k^p are stored SIGNED and 64-wide (s = sign(val)*|val|^p); the
// sim/opp 128-wide halves are reconstructed with relu/-relu during LDS
// staging. Output d_out is FLOAT32 (reference output dtype).
//
// R7 changes vs R6 (604 us; R6's 128x64-wave regressed, reverting to R5
// skeleton = 590 us, gemm0 198 us @ MfmaUtil 35%):
//  - Port arithmetic for R5 (per CU per 32-k tile): LDS ~2120 cyc (reads
//    1540 + staging writes 580) vs MFMA 1242 cyc -> LDS port is the binder
//    (matches MfmaUtil ~35% across R2-R5's four schedules).
//  - gemm_kernel: B operand taken OUT of LDS. Waves load their own B frags
//    directly global->VGPR (blocked layout = 256B-contiguous coalesced,
//    L2/L3-resident 4.6MB weights), register-double-buffered 1 K-tile
//    ahead. A stays via global_load_lds, triple-buffered (24KB LDS).
//    New budget: LDS ~965 cyc < MFMA 1242 -> MFMA-bound. One barrier/tile,
//    counted vmcnt, never 0 in steady state. Geometry = R5 (BM=128,
//    BN=256, BK=32, 8 waves 2Mx4N, 64x64/wave, 2 blocks/CU).
// ---------------------------------------------------------------------------

typedef _Float16 f16;
typedef __attribute__((ext_vector_type(4))) float f32x4;
typedef __attribute__((ext_vector_type(8))) _Float16 f16x8;
typedef __attribute__((ext_vector_type(4))) _Float16 f16x4;

__device__ __forceinline__ void mfma(f32x4& c, f16x8 a, f16x8 b) {
  c = __builtin_amdgcn_mfma_f32_16x16x32_f16(a, b, c, 0, 0, 0);
}

// Async global->LDS, 16 bytes per lane. LDS dest is wave-uniform base +
// lane*16; global src is per-lane. Layouts here are exact linear copies.
__device__ __forceinline__ void gload_lds16(const f16* g, f16* l) {
  __builtin_amdgcn_global_load_lds(
      (__attribute__((address_space(1))) void*)g,
      (__attribute__((address_space(3))) void*)l, 16, 0, 0);
}

__device__ __forceinline__ f16x8 relu8(f16x8 v) {
  f16x8 r;
#pragma unroll
  for (int u = 0; u < 8; ++u) r[u] = (v[u] > (f16)0) ? v[u] : (f16)0;
  return r;
}
__device__ __forceinline__ f16x8 nrelu8(f16x8 v) {
  f16x8 r;
#pragma unroll
  for (int u = 0; u < 8; ++u) r[u] = (v[u] < (f16)0) ? (f16)(-v[u]) : (f16)0;
  return r;
}

// ---------------------------------------------------------------------------
__global__ void prep_scalars_kernel(const float* __restrict__ scale_p,
                                    const float* __restrict__ power_p,
                                    float* __restrict__ iscale,
                                    float* __restrict__ powr) {
  int c = blockIdx.x * 256 + threadIdx.x;
  if (c < 768) {
    float sp = scale_p[c];
    float s = (sp > 20.f) ? sp : log1pf(__expf(sp));
    iscale[c] = 1.f / s;
    powr[c] = 1.f + 4.f / (1.f + __expf(-power_p[c]));
  }
}

// x (fp32 row-major 32768x768) -> f16 blocked. grid (12, 256), block 256.
__global__ __launch_bounds__(256) void cast_x_kernel(const float* __restrict__ x,
                                                     f16* __restrict__ xblk) {
  __shared__ f16 tile[128 * 72];  // stride 72 breaks bank conflicts
  const int kb = blockIdx.x, mt = blockIdx.y, t = threadIdx.x;
  const float* xp = x + (size_t)mt * 128 * 768 + kb * 64;
#pragma unroll
  for (int it = 0; it < 8; ++it) {
    int idx = it * 256 + t;
    int row = idx >> 4, kc4 = (idx & 15) * 4;
    f32x4 v = *(const f32x4*)(xp + (size_t)row * 768 + kc4);
    f16x4 h;
    h[0] = (f16)v[0]; h[1] = (f16)v[1]; h[2] = (f16)v[2]; h[3] = (f16)v[3];
    *(f16x4*)(tile + row * 72 + kc4) = h;
  }
  __syncthreads();
  f16* op = xblk + (size_t)mt * 98304 + kb * 8192;
#pragma unroll
  for (int it = 0; it < 4; ++it) {
    int c = it * 256 + t;
    int kchunk = c >> 7, m = c & 127;
    f16x4 lo = *(const f16x4*)(tile + m * 72 + kchunk * 8);
    f16x4 hi = *(const f16x4*)(tile + m * 72 + kchunk * 8 + 4);
    *(f16x4*)(op + c * 8) = lo;
    *(f16x4*)(op + c * 8 + 4) = hi;
  }
}

// W (fp32, R x Cc, row-major) -> W^T f16 blocked at output-col offset col_off.
// grid (Cc/32, R/32), block 256.
__global__ __launch_bounds__(256) void transpose_w_kernel(const float* __restrict__ W,
                                                          f16* __restrict__ outblk,
                                                          int Cc, int col_off) {
  __shared__ float tile[32][33];
  const int c0 = blockIdx.x * 32, r0 = blockIdx.y * 32, t = threadIdx.x;
#pragma unroll
  for (int it = 0; it < 4; ++it) {
    int rr = it * 8 + (t >> 5), cc = t & 31;
    tile[rr][cc] = W[(size_t)(r0 + rr) * Cc + c0 + cc];
  }
  __syncthreads();
  if (t < 128) {
    int cl = t >> 2, rb = t & 3;
    int cg = col_off + c0 + cl;
    int rg = r0 + rb * 8;
    f16x4 v0, v1;
#pragma unroll
    for (int u = 0; u < 4; ++u) v0[u] = (f16)tile[rb * 8 + u][cl];
#pragma unroll
    for (int u = 0; u < 4; ++u) v1[u] = (f16)tile[rb * 8 + 4 + u][cl];
    size_t base = (size_t)(cg >> 7) * 98304 + (size_t)(rg >> 3) * 1024 +
                  (size_t)(cg & 127) * 8;
    *(f16x4*)(outblk + base) = v0;
    *(f16x4*)(outblk + base + 4) = v1;
  }
}

// ---------------------------------------------------------------------------
// Main GEMM. BM=128, BN=256, BK=32, 8 waves (2M x 4N), per-wave 64x64
// (acc 4x4). A through triple-buffered LDS (3 x 8KB = 24KB); B loaded
// DIRECTLY global->VGPR per wave (coalesced 256B segments from the blocked
// layout; 4.6MB weights stay L2/L3-resident), register-double-buffered one
// K-tile ahead. 24 K-tiles; per tile (1 barrier):
//   STAGE_A(buf[j+2]) (1 gload_lds, 8KB)  ||  LOADB(bfNext, j+1) (4 b128)
//   4x ds_read A frags (tile j); compiler inserts lgkm/vm waits for deps
//   setprio(1); 16 MFMA (af, bfCur); setprio(0)
//   s_waitcnt vmcnt(5)  // own A(j+1) landed; A(j+2)+B(j+1) stay in flight
//   s_barrier           // A(j+1) visible to all; buf(j-1) WAR-safe
// MODE 0: X@[Wqg|Wkv] (NN=3072), fused pola epilogue. grid (12, 256).
// MODE 1: pre@Wproj (NN=768), +bproj, FLOAT32 out.     grid (3, 256).
template <int MODE>
__global__ __launch_bounds__(512, 4) void gemm_kernel(
    const f16* __restrict__ Ablk, const f16* __restrict__ Bblk,
    const float* __restrict__ powr, const float* __restrict__ iscale,
    const float* __restrict__ pos_enc, const float* __restrict__ bproj,
    f16* __restrict__ qpow, f16* __restrict__ gbuf, f16* __restrict__ kpow,
    f16* __restrict__ vt, float* __restrict__ outp) {
  constexpr int STR = 4096;              // f16 per A buffer (8KB)
  __shared__ f16 smem[3 * STR];          // 24KB
  const int t = threadIdx.x;
  const int wid = t >> 6, lane = t & 63;
  const int c16 = lane & 15, q = lane >> 4;
  const int ntile = blockIdx.x, mtile = blockIdx.y;
  const int wm = wid >> 2, wn = wid & 3;       // 2M x 4N
  const int bh2 = wn >> 1, bc = (wn & 1) * 64; // B half / 64-col base
  const f16* Ap = Ablk + (size_t)mtile * 98304;
  const f16* Bp = Bblk + (size_t)ntile * 196608;
  // Per-lane B base: col (bc + c16), k-chunk q. Frag ni at +ni*128 f16;
  // K-tile k0 at +(k0/8)*1024 f16.
  const f16* Bl = Bp + (size_t)bh2 * 98304 + q * 1024 + (bc + c16) * 8;

  auto STAGE_A = [&](int buf, int k0) {
    gload_lds16(Ap + (size_t)(k0 >> 3) * 1024 + (size_t)t * 8,
                smem + buf * STR + (size_t)t * 8);
  };
  auto LOADB = [&](f16x8* bf, int k0) {
    const f16* bp = Bl + (size_t)(k0 >> 3) * 1024;
#pragma unroll
    for (int ni = 0; ni < 4; ++ni) bf[ni] = *(const f16x8*)(bp + ni * 128);
  };

  f32x4 acc[4][4];
#pragma unroll
  for (int i = 0; i < 4; ++i)
#pragma unroll
    for (int j = 0; j < 4; ++j) acc[i][j] = (f32x4){0.f, 0.f, 0.f, 0.f};

  f16x8 bfA[4], bfB[4];

  STAGE_A(0, 0);
  LOADB(bfA, 0);
  STAGE_A(1, 32);
  asm volatile("s_waitcnt vmcnt(1)");  // A(0)+B(0) landed; A(1) in flight
  __builtin_amdgcn_sched_barrier(0);
  __builtin_amdgcn_s_barrier();
  __builtin_amdgcn_sched_barrier(0);

  int cur = 0, nn = 2;
#pragma unroll 1
  for (int jj = 0; jj < 12; ++jj) {
    const int j0 = jj * 2, j1 = j0 + 1;
    // ---- tile j0: consume bfA, prefetch bfB = B(j0+1)
    if (j0 < 22) STAGE_A(nn, (j0 + 2) * 32);
    LOADB(bfB, j1 * 32);  // j1 <= 23 always
    {
      const f16* A_ = smem + cur * STR + q * 1024;
      f16x8 af[4];
#pragma unroll
      for (int mi = 0; mi < 4; ++mi)
        af[mi] = *(const f16x8*)(A_ + (wm * 64 + mi * 16 + c16) * 8);
      __builtin_amdgcn_s_setprio(1);
#pragma unroll
      for (int mi = 0; mi < 4; ++mi)
#pragma unroll
        for (int ni = 0; ni < 4; ++ni) mfma(acc[mi][ni], af[mi], bfA[ni]);
      __builtin_amdgcn_s_setprio(0);
    }
    if (j0 < 22) asm volatile("s_waitcnt vmcnt(5)");
    else         asm volatile("s_waitcnt vmcnt(4)");
    __builtin_amdgcn_sched_barrier(0);
    __builtin_amdgcn_s_barrier();
    __builtin_amdgcn_sched_barrier(0);
    cur = (cur == 2) ? 0 : cur + 1;
    nn = (nn == 2) ? 0 : nn + 1;
    // ---- tile j1: consume bfB, prefetch bfA = B(j1+1)
    if (j1 < 22) STAGE_A(nn, (j1 + 2) * 32);
    if (j1 < 23) LOADB(bfA, (j1 + 1) * 32);
    {
      const f16* A_ = smem + cur * STR + q * 1024;
      f16x8 af[4];
#pragma unroll
      for (int mi = 0; mi < 4; ++mi)
        af[mi] = *(const f16x8*)(A_ + (wm * 64 + mi * 16 + c16) * 8);
      __builtin_amdgcn_s_setprio(1);
#pragma unroll
      for (int mi = 0; mi < 4; ++mi)
#pragma unroll
        for (int ni = 0; ni < 4; ++ni) mfma(acc[mi][ni], af[mi], bfB[ni]);
      __builtin_amdgcn_s_setprio(0);
    }
    if (j1 < 23) {
      if (j1 < 22) asm volatile("s_waitcnt vmcnt(5)");
      else         asm volatile("s_waitcnt vmcnt(4)");
      __builtin_amdgcn_sched_barrier(0);
      __builtin_amdgcn_s_barrier();
      __builtin_amdgcn_sched_barrier(0);
    }
    cur = (cur == 2) ? 0 : cur + 1;
    nn = (nn == 2) ? 0 : nn + 1;
  }

  if (MODE == 0) {
    // 3072 output cols: 0..767 q, 768..1535 g, 1536..2303 k, 2304..3071 v
    const int sec = ntile / 3;
    const int csb = (ntile - sec * 3) * 256;
    const int b = mtile >> 5;
    const int nim0 = (mtile & 31) * 128;
#pragma unroll
    for (int mi = 0; mi < 4; ++mi) {
      const int nloc = nim0 + wm * 64 + mi * 16 + q * 4;  // + r2, in [0,4096)
#pragma unroll
      for (int ni = 0; ni < 4; ++ni) {
        const int cs = csb + wn * 64 + ni * 16 + c16;  // 0..767 within section
        const int h = cs >> 6, d = cs & 63;
        const int bh = b * 12 + h;
        if (sec == 0) {  // q -> signed q^p, blocked [bh][n/128][d/8][n%128][d%8]
          const float p = powr[cs], isc = iscale[cs];
          const size_t qb2 = (size_t)bh * 262144 + (size_t)(nloc >> 7) * 8192;
          const int dpo = (d >> 3) * 1024 + (d & 7);
#pragma unroll
          for (int r2 = 0; r2 < 4; ++r2) {
            float val = acc[mi][ni][r2] * isc;
            float av = fabsf(val);
            float e = (av > 0.f) ? exp2f(p * __log2f(av)) : 0.f;
            float s = (val > 0.f) ? e : ((val < 0.f) ? -e : 0.f);
            int mrow = (nloc + r2) & 127;
            qpow[qb2 + mrow * 8 + dpo] = (f16)s;
          }
        } else if (sec == 1) {  // g -> blocked like pre/qpow (xa coalesced)
#pragma unroll
          for (int r2 = 0; r2 < 4; ++r2) {
            const int tok = b * 4096 + nloc + r2;
            gbuf[(size_t)(tok >> 7) * 98304 + (size_t)(cs >> 3) * 1024 +
                 (tok & 127) * 8 + (cs & 7)] = (f16)acc[mi][ni][r2];
          }
        } else if (sec == 2) {  // k -> signed k^p, blocked [bh][n/8][d][n%8]
          const float p = powr[cs], isc = iscale[cs];
          f16x4 pk;
#pragma unroll
          for (int r2 = 0; r2 < 4; ++r2) {
            int n = nloc + r2;
            float val = (acc[mi][ni][r2] + pos_enc[(size_t)n * 768 + cs]) * isc;
            float av = fabsf(val);
            float e = (av > 0.f) ? exp2f(p * __log2f(av)) : 0.f;
            pk[r2] = (f16)((val > 0.f) ? e : ((val < 0.f) ? -e : 0.f));
          }
          const size_t kb2 =
              (size_t)bh * 262144 + (size_t)(nloc >> 3) * 512 + (nloc & 7);
          *(f16x4*)(kpow + kb2 + (size_t)d * 8) = pk;
        } else {  // v -> vT plane-major [bh][d][n]
          f16x4 vv4;
#pragma unroll
          for (int r2 = 0; r2 < 4; ++r2) vv4[r2] = (f16)acc[mi][ni][r2];
          *(f16x4*)(vt + (size_t)(bh * 64 + d) * 4096 + nloc) = vv4;
        }
      }
    }
  } else {
#pragma unroll
    for (int mi = 0; mi < 4; ++mi) {
      const int tok0 = mtile * 128 + wm * 64 + mi * 16 + q * 4;
#pragma unroll
      for (int ni = 0; ni < 4; ++ni) {
        const int col = ntile * 256 + wn * 64 + ni * 16 + c16;
        const float bb = bproj[col];
#pragma unroll
        for (int r2 = 0; r2 < 4; ++r2)
          outp[(size_t)(tok0 + r2) * 768 + col] = acc[mi][ni][r2] + bb;
      }
    }
  }
}

// OUT[vv][kk] = sum_n v[n][vv]*k_cat[n][kk], per (bh, split) over 1024 n.
// Fuses ksum (sum over n of k_cat columns) into the already-loaded k regs.
// grid (96, 4), block 256. Partials: kvp[bh][split][64][128],
// ksp[bh][split][128] (kk<64 = sum relu, kk>=64 = sum nrelu).
__global__ __launch_bounds__(256) void kv_kernel(const f16* __restrict__ kpow,
                                                 const f16* __restrict__ vt,
                                                 float* __restrict__ kvp,
                                                 float* __restrict__ ksp) {
  __shared__ f16 Ks[8192];  // [nchunk8][kk128][8]
  __shared__ f16 Vs[4096];  // [nchunk8][vv64 xor-swizzled][8]
  __shared__ float rp[256], rn[256];
  const int bh = blockIdx.x, split = blockIdx.y, t = threadIdx.x;
  const int wave = t >> 6, lane = t & 63;
  const int c16 = lane & 15, q = lane >> 4;
  const f16* kb = kpow + (size_t)bh * 262144;
  const f16* vb = vt + (size_t)bh * 64 * 4096;
  f32x4 acc[4][2];
#pragma unroll
  for (int i = 0; i < 4; ++i)
#pragma unroll
    for (int j = 0; j < 2; ++j) acc[i][j] = (f32x4){0.f, 0.f, 0.f, 0.f};
  float sp = 0.f, sn = 0.f;  // ksum partials, this thread's d = t&63

  const int n_beg = split * 1024, n_end = n_beg + 1024;
  for (int n0 = n_beg; n0 < n_end; n0 += 64) {
    f16x8 kr[2], vr[2];
#pragma unroll
    for (int r = 0; r < 2; ++r)
      kr[r] = *(const f16x8*)(kb + (size_t)n0 * 64 + (size_t)(r * 256 + t) * 8);
#pragma unroll
    for (int r = 0; r < 2; ++r) {
      int cc = r * 256 + t;
      int vv = cc >> 3, nc = cc & 7;
      vr[r] = *(const f16x8*)(vb + (size_t)vv * 4096 + n0 + nc * 8);
    }
    // fused ksum: each kr[r] is 8 consecutive n at column d = t&63
#pragma unroll
    for (int r = 0; r < 2; ++r)
#pragma unroll
      for (int u = 0; u < 8; ++u) {
        float f = (float)kr[r][u];
        sp += (f > 0.f) ? f : 0.f;
        sn += (f < 0.f) ? -f : 0.f;
      }
    __syncthreads();
#pragma unroll
    for (int r = 0; r < 2; ++r) {
      int cp = r * 256 + t;
      int nch = cp >> 6, d = cp & 63;
      *(f16x8*)(Ks + (size_t)(nch * 1024 + d * 8)) = relu8(kr[r]);
      *(f16x8*)(Ks + (size_t)(nch * 1024 + (d + 64) * 8)) = nrelu8(kr[r]);
    }
#pragma unroll
    for (int r = 0; r < 2; ++r) {
      int cc = r * 256 + t;
      int vv = cc >> 3, nc = cc & 7;
      *(f16x8*)(Vs + (size_t)(nc * 64 + (vv ^ nc)) * 8) = vr[r];
    }
    __syncthreads();
#pragma unroll
    for (int s = 0; s < 2; ++s) {
      f16x8 af[4], bf2[2];
#pragma unroll
      for (int i = 0; i < 4; ++i) {
        int m = i * 16 + c16, nc2 = s * 4 + q;
        af[i] = *(const f16x8*)(Vs + (nc2 * 64 + (m ^ nc2)) * 8);
      }
#pragma unroll
      for (int j = 0; j < 2; ++j)
        bf2[j] = *(const f16x8*)(Ks + ((s * 4 + q) * 128 + wave * 32 + j * 16 + c16) * 8);
#pragma unroll
      for (int i = 0; i < 4; ++i)
#pragma unroll
        for (int j = 0; j < 2; ++j) mfma(acc[i][j], af[i], bf2[j]);
    }
    __syncthreads();
  }
  float* kvb = kvp + (size_t)(bh * 4 + split) * 8192;
#pragma unroll
  for (int i = 0; i < 4; ++i)
#pragma unroll
    for (int j = 0; j < 2; ++j) {
      int kk = wave * 32 + j * 16 + c16;
      int vv0 = i * 16 + q * 4;
#pragma unroll
      for (int r2 = 0; r2 < 4; ++r2)
        kvb[(size_t)(vv0 + r2) * 128 + kk] = acc[i][j][r2];
    }
  rp[t] = sp; rn[t] = sn;
  __syncthreads();
  if (t < 64) {
    float* ko = ksp + (size_t)(bh * 4 + split) * 128;
    ko[t] = rp[t] + rp[t + 64] + rp[t + 128] + rp[t + 192];
    ko[64 + t] = rn[t] + rn[t + 64] + rn[t + 128] + rn[t + 192];
  }
}

// Build BxT[bh][80][128] f16 from the 4 split partials: xa-GEMM B-operand
// rows: x_sim cols 0..31, x_opp 32..63, denominators 64..65, zero pad 66..79.
// grid 96, block 128.
__global__ void bx_kernel(const float* __restrict__ kvp,
                          const float* __restrict__ ksp, f16* __restrict__ bxt) {
  const int bh = blockIdx.x, kk = threadIdx.x;
  const float inv_n = 1.f / 4096.f;
  const float* kv0 = kvp + (size_t)bh * 4 * 8192;
  const float* ks0 = ksp + (size_t)bh * 4 * 128;
  f16* ob = bxt + (size_t)bh * 80 * 128;
  for (int nn = 0; nn < 32; ++nn) {
    float v = kv0[nn * 128 + kk] + kv0[8192 + nn * 128 + kk] +
              kv0[16384 + nn * 128 + kk] + kv0[24576 + nn * 128 + kk];
    ob[nn * 128 + kk] = (f16)(v * inv_n);
  }
  const int kx = kk ^ 64;
  for (int nn = 32; nn < 64; ++nn) {
    float v = kv0[nn * 128 + kx] + kv0[8192 + nn * 128 + kx] +
              kv0[16384 + nn * 128 + kx] + kv0[24576 + nn * 128 + kx];
    ob[nn * 128 + kk] = (f16)(v * inv_n);
  }
  float s0 = ks0[kk] + ks0[128 + kk] + ks0[256 + kk] + ks0[384 + kk];
  ob[64 * 128 + kk] = (f16)(s0 * inv_n);
  float s1 = ks0[kx] + ks0[128 + kx] + ks0[256 + kx] + ks0[384 + kx];
  ob[65 * 128 + kk] = (f16)(s1 * inv_n);
  for (int nn = 66; nn < 80; ++nn) ob[nn * 128 + kk] = (f16)0.f;
}

// Depthwise 5x5 SAME conv on 64x64 images. grid 96*64.
__global__ __launch_bounds__(256) void conv_kernel(const f16* __restrict__ vt,
                                                   const float* __restrict__ w,
                                                   const float* __restrict__ bias,
                                                   f16* __restrict__ vpos) {
  __shared__ float img[68 * 69];
  const int blk = blockIdx.x;
  const int d = blk & 63, bh = blk >> 6;
  const f16* src = vt + (size_t)(bh * 64 + d) * 4096;
  // interior: vectorized f16x4 loads (64 cols = 16 quads per row)
  for (int i = threadIdx.x; i < 68 * 16; i += 256) {
    int yy = i >> 4, g4 = i & 15;
    int y = yy - 2;
    float v0 = 0.f, v1 = 0.f, v2 = 0.f, v3 = 0.f;
    if ((unsigned)y < 64u) {
      f16x4 v = *(const f16x4*)(src + y * 64 + g4 * 4);
      v0 = (float)v[0]; v1 = (float)v[1]; v2 = (float)v[2]; v3 = (float)v[3];
    }
    float* row = img + yy * 69 + 2 + g4 * 4;
    row[0] = v0; row[1] = v1; row[2] = v2; row[3] = v3;
  }
  // border cols x = -2,-1,64,65 -> zeros
  for (int i = threadIdx.x; i < 68 * 4; i += 256) {
    int yy = i >> 2, c = i & 3;
    int xx = (c < 2) ? c : 64 + c;  // 0,1,66,67
    img[yy * 69 + xx] = 0.f;
  }
  float wr[25];
#pragma unroll
  for (int k = 0; k < 25; ++k) wr[k] = w[d * 25 + k];
  const float bb = bias[d];
  __syncthreads();
  f16* dst = vpos + (size_t)(bh * 64 + d) * 4096;
  for (int g4 = threadIdx.x; g4 < 1024; g4 += 256) {
    int y = g4 >> 4, x4 = (g4 & 15) * 4;
    float o0 = bb, o1 = bb, o2 = bb, o3 = bb;
#pragma unroll
    for (int ky = 0; ky < 5; ++ky) {
      const float* row = img + (y + ky) * 69 + x4;
      float r[8];
#pragma unroll
      for (int u = 0; u < 8; ++u) r[u] = row[u];
#pragma unroll
      for (int kx = 0; kx < 5; ++kx) {
        float wv = wr[ky * 5 + kx];
        o0 += r[kx] * wv;
        o1 += r[kx + 1] * wv;
        o2 += r[kx + 2] * wv;
        o3 += r[kx + 3] * wv;
      }
    }
    f16x4 st;
    st[0] = (f16)o0; st[1] = (f16)o1; st[2] = (f16)o2; st[3] = (f16)o3;
    *(f16x4*)(dst + y * 64 + x4) = st;
  }
}

// xa = q_sim @ Bx (4096x80x128 per bh), z-normalize, add v_pos, gate by g,
// write `pre` blocked for the projection GEMM. grid (32, 96), block 256.
// vpos tile staged via Ps; gbuf tile and the output tile staged through the
// dead Qs buffer -> all global IO is coalesced b128.
__global__ __launch_bounds__(256) void xa_kernel(
    const f16* __restrict__ qpow, const f16* __restrict__ bxt,
    const f16* __restrict__ vpos, const f16* __restrict__ gbuf,
    f16* __restrict__ pre) {
  __shared__ f16 Qs[16384];     // q_sim tile; after MFMA: [0:8192)=G, [8192:16384)=OUT
  __shared__ f16 Ps[64 * 134];  // vpos tile [col][n], stride 134 vs banks
  __shared__ float zs[256];
  const int nb = blockIdx.x, bh = blockIdx.y;
  const int b = bh / 12, h = bh % 12;
  const int t = threadIdx.x;
  const int wave = t >> 6, lane = t & 63;
  const int c16 = lane & 15, q = lane >> 4;
  const f16* qb = qpow + (size_t)bh * 262144 + (size_t)nb * 8192;
  // blocked-tile base shared by gbuf and pre: tok0 = b*4096+nb*128, kchunks h*8..
  const size_t gp2 = (size_t)(b * 32 + nb) * 98304 + (size_t)(h * 8) * 1024;
  f16x8 qr[4], gr[4];
#pragma unroll
  for (int r = 0; r < 4; ++r)
    qr[r] = *(const f16x8*)(qb + (size_t)(r * 256 + t) * 8);
#pragma unroll
  for (int r = 0; r < 4; ++r)
    gr[r] = *(const f16x8*)(gbuf + gp2 + (size_t)(r * 256 + t) * 8);
#pragma unroll
  for (int r = 0; r < 4; ++r) {
    int c = r * 256 + t;
    int dch = c >> 7, row = c & 127;
    *(f16x8*)(Qs + (size_t)(dch * 1024 + row * 8)) = relu8(qr[r]);
    *(f16x8*)(Qs + (size_t)((dch + 8) * 1024 + row * 8)) = nrelu8(qr[r]);
  }
  // stage vpos[bh][col][nb*128 .. +128] -> Ps[col][n], coalesced 16B loads
  {
    const f16* vpb = vpos + (size_t)bh * 262144 + (size_t)nb * 128;
#pragma unroll
    for (int it = 0; it < 4; ++it) {
      int idx = it * 256 + t;          // 1024 chunks of 8 f16
      int col = idx >> 4, nc = idx & 15;
      f16x8 v = *(const f16x8*)(vpb + (size_t)col * 4096 + nc * 8);
      *(f16x8*)(Ps + col * 134 + nc * 8) = v;
    }
  }
  __syncthreads();
  f32x4 acc[2][5];
#pragma unroll
  for (int i = 0; i < 2; ++i)
#pragma unroll
    for (int j = 0; j < 5; ++j) acc[i][j] = (f32x4){0.f, 0.f, 0.f, 0.f};
  const f16* bx = bxt + (size_t)bh * 80 * 128;
#pragma unroll
  for (int s = 0; s < 4; ++s) {
    f16x8 af[2], bf5[5];
#pragma unroll
    for (int i = 0; i < 2; ++i)
      af[i] = *(const f16x8*)(Qs + ((s * 4 + q) * 1024 + (wave * 32 + i * 16 + c16) * 8));
#pragma unroll
    for (int j = 0; j < 5; ++j)
      bf5[j] = *(const f16x8*)(bx + (size_t)(j * 16 + c16) * 128 + s * 32 + q * 8);
#pragma unroll
    for (int i = 0; i < 2; ++i)
#pragma unroll
      for (int j = 0; j < 5; ++j) mfma(acc[i][j], af[i], bf5[j]);
  }
  // denominators: tile col 4 -> col 64 (sim) at c16==0, col 65 (opp) at c16==1
  if (c16 < 2) {
#pragma unroll
    for (int i = 0; i < 2; ++i) {
      int mloc = wave * 32 + i * 16 + q * 4;
#pragma unroll
      for (int r2 = 0; r2 < 4; ++r2) zs[(mloc + r2) * 2 + c16] = acc[i][4][r2];
    }
  }
  __syncthreads();  // all waves done with Qs -> reuse as G / OUT staging
  f16* Gs = Qs;          // [kc8][m128][dd8] linear = global blocked layout
  f16* Os = Qs + 8192;
#pragma unroll
  for (int r = 0; r < 4; ++r)
    *(f16x8*)(Gs + (size_t)(r * 256 + t) * 8) = gr[r];
  __syncthreads();
#pragma unroll
  for (int i = 0; i < 2; ++i) {
    const int mbase = wave * 32 + i * 16 + q * 4;
#pragma unroll
    for (int j = 0; j < 4; ++j) {
      const int col = j * 16 + c16;  // 0..63
      const int zsel = col >> 5;
      const int gidx = (col >> 3) * 1024 + (col & 7);
#pragma unroll
      for (int r2 = 0; r2 < 4; ++r2) {
        const int mloc = mbase + r2;
        const float den = zs[mloc * 2 + zsel];
        const float xav = acc[i][j][r2] / (den + 1e-6f);
        const float vp = (float)Ps[col * 134 + mloc];
        const float gg = (float)Gs[gidx + mloc * 8];
        Os[gidx + mloc * 8] = (f16)((xav + vp) * gg);
      }
    }
  }
  __syncthreads();
#pragma unroll
  for (int r = 0; r < 4; ++r)
    *(f16x8*)(pre + gp2 + (size_t)(r * 256 + t) * 8) =
        *(const f16x8*)(Os + (size_t)(r * 256 + t) * 8);
}

// ---------------------------------------------------------------------------
extern "C" void kernel_launch(void* const* d_in, const int* in_sizes, int n_in,
                              void* d_out, int out_size, void* d_ws, size_t ws_size,
                              hipStream_t stream) {
  const float* x       = (const float*)d_in[0];
  const float* Wqg     = (const float*)d_in[1];
  const float* Wkv     = (const float*)d_in[2];
  const float* Wproj   = (const float*)d_in[3];
  const float* bproj   = (const float*)d_in[4];
  const float* dwc_w   = (const float*)d_in[5];
  const float* dwc_b   = (const float*)d_in[6];
  const float* power_p = (const float*)d_in[7];
  const float* scale_p = (const float*)d_in[8];
  const float* pos_enc = (const float*)d_in[9];
  float* outp = (float*)d_out;  // FLOAT32 output (reference output dtype)

  char* ws = (char*)d_ws;
  // Workspace layout (bytes). Total ~247.6 MiB.
  constexpr size_t o_qpow = 0;          // 50331648  signed q^p
  constexpr size_t o_kpow = 50331648;   // 50331648  signed k^p (later: vpos)
  constexpr size_t o_vt   = 100663296;  // 50331648  v transposed planes
  constexpr size_t o_gbuf = 150994944;  // 50331648  gate, blocked layout
  constexpr size_t o_xblk = 201326592;  // 50331648  x blocked (later: kvp/ksp, then pre)
  constexpr size_t o_wta  = 251658240;  // 4718592   [Wqg|Wkv]^T
  constexpr size_t o_wtp  = 256376832;  // 1179648   Wproj^T
  constexpr size_t o_isc  = 257556480;  // 3072+pad
  constexpr size_t o_pwr  = 257560576;  // 3072+pad
  constexpr size_t o_bxt  = 257564672;  // 1966080

  f16*   qpow = (f16*)(ws + o_qpow);
  f16*   kpow = (f16*)(ws + o_kpow);
  f16*   vt   = (f16*)(ws + o_vt);
  f16*   gbuf = (f16*)(ws + o_gbuf);
  f16*   xblk = (f16*)(ws + o_xblk);
  f16*   wta  = (f16*)(ws + o_wta);
  f16*   wtp  = (f16*)(ws + o_wtp);
  float* isc  = (float*)(ws + o_isc);
  float* pwr  = (float*)(ws + o_pwr);
  f16*   bxt  = (f16*)(ws + o_bxt);
  // Aliases (stream-ordered lifetimes):
  //   xblk (gemm<0> input) dies after gemm<0>; kvp/ksp live there until bx;
  //   then xa writes pre over the same region. kpow dies after kv -> vpos.
  float* kvp  = (float*)(ws + o_xblk);              // 96*4*8192*4 = 12.6 MB
  float* ksp  = (float*)(ws + o_xblk + 12582912);   // 96*4*128*4  = 0.2 MB
  f16*   vpos = kpow;
  f16*   pre  = xblk;

  prep_scalars_kernel<<<dim3(3), 256, 0, stream>>>(scale_p, power_p, isc, pwr);
  cast_x_kernel<<<dim3(12, 256), 256, 0, stream>>>(x, xblk);
  transpose_w_kernel<<<dim3(48, 24), 256, 0, stream>>>(Wqg, wta, 1536, 0);
  transpose_w_kernel<<<dim3(48, 24), 256, 0, stream>>>(Wkv, wta, 1536, 1536);
  transpose_w_kernel<<<dim3(24, 24), 256, 0, stream>>>(Wproj, wtp, 768, 0);
  gemm_kernel<0><<<dim3(12, 256), 512, 0, stream>>>(
      xblk, wta, pwr, isc, pos_enc, nullptr, qpow, gbuf, kpow, vt, nullptr);
  kv_kernel<<<dim3(96, 4), 256, 0, stream>>>(kpow, vt, kvp, ksp);
  bx_kernel<<<96, 128, 0, stream>>>(kvp, ksp, bxt);
  conv_kernel<<<6144, 256, 0, stream>>>(vt, dwc_w, dwc_b, vpos);
  xa_kernel<<<dim3(32, 96), 256, 0, stream>>>(qpow, bxt, vpos, gbuf, pre);
  gemm_kernel<1><<<dim3(3, 256), 512, 0, stream>>>(
      pre, wtp, nullptr, nullptr, nullptr, bproj, nullptr, nullptr, nullptr,
      nullptr, outp);
}

// Round 9
// 571.110 us; speedup vs baseline: 1.0737x; 1.0737x over previous
//
#include <hip/hip_runtime.h>

// ---------------------------------------------------------------------------
// PolaLinearAttention on MI355X (gfx950), f16 MFMA pipeline.
// B=8 N=4096 C=768 Hn=12 hd=64. All matmuls via v_mfma_f32_16x16x32_f16.
// Blocked operand layout for MFMA operands (128-row tiles):
//   off(row, k) = (row/128)*(128*K) + (k/8)*1024 + (row%128)*8 + (k%8)
// q^p / k^p are stored SIGNED and 64-wide (s = sign(val)*|val|^p); the
// sim/opp 128-wide halves are reconstructed with relu/-relu during LDS
// staging. Output d_out is FLOAT32 (reference output dtype).
//
// R9 == R8 resubmission (R8 bench failed: GPUAcquisitionTimeout, no data).
// R8 changes vs R7 (613; best = R5 590 us, gemm0 198 us, FETCH 267 MB):
//  - K-loop: reverted to R5's triple-buffered vmcnt(3) pipeline (best).
//  - Diagnosis: FETCH_SIZE 267 MB vs ~66 MB ideal reads. The excess ~200MB
//    = write volume -> read-for-ownership on partial-cacheline epilogue
//    stores (qpow scalar f16 @16B, kpow f16x4 @8B/1KB-stride, vt f16x4
//    @8B across planes, gemm1 scalar f32). RFO also doubles write cost.
//  - Fix: epilogue LDS staging. After the K-loop the 72KB LDS is dead;
//    each section's 128x256 tile maps to CONTIGUOUS global regions
//    (q/k: 4x16KB, g: 64KB, v: 256x256B rows). Stage values in LDS in
//    exact global layout -> barrier -> full-line f16x8/f32x4 block copy.
//    gemm1 stages 64-row fp32 halves (2x64KB passes).
// ---------------------------------------------------------------------------

typedef _Float16 f16;
typedef __attribute__((ext_vector_type(4))) float f32x4;
typedef __attribute__((ext_vector_type(8))) _Float16 f16x8;
typedef __attribute__((ext_vector_type(4))) _Float16 f16x4;

__device__ __forceinline__ void mfma(f32x4& c, f16x8 a, f16x8 b) {
  c = __builtin_amdgcn_mfma_f32_16x16x32_f16(a, b, c, 0, 0, 0);
}

// Async global->LDS, 16 bytes per lane. LDS dest is wave-uniform base +
// lane*16; global src is per-lane. Layouts here are exact linear copies.
__device__ __forceinline__ void gload_lds16(const f16* g, f16* l) {
  __builtin_amdgcn_global_load_lds(
      (__attribute__((address_space(1))) void*)g,
      (__attribute__((address_space(3))) void*)l, 16, 0, 0);
}

__device__ __forceinline__ f16x8 relu8(f16x8 v) {
  f16x8 r;
#pragma unroll
  for (int u = 0; u < 8; ++u) r[u] = (v[u] > (f16)0) ? v[u] : (f16)0;
  return r;
}
__device__ __forceinline__ f16x8 nrelu8(f16x8 v) {
  f16x8 r;
#pragma unroll
  for (int u = 0; u < 8; ++u) r[u] = (v[u] < (f16)0) ? (f16)(-v[u]) : (f16)0;
  return r;
}

// ---------------------------------------------------------------------------
__global__ void prep_scalars_kernel(const float* __restrict__ scale_p,
                                    const float* __restrict__ power_p,
                                    float* __restrict__ iscale,
                                    float* __restrict__ powr) {
  int c = blockIdx.x * 256 + threadIdx.x;
  if (c < 768) {
    float sp = scale_p[c];
    float s = (sp > 20.f) ? sp : log1pf(__expf(sp));
    iscale[c] = 1.f / s;
    powr[c] = 1.f + 4.f / (1.f + __expf(-power_p[c]));
  }
}

// x (fp32 row-major 32768x768) -> f16 blocked. grid (12, 256), block 256.
__global__ __launch_bounds__(256) void cast_x_kernel(const float* __restrict__ x,
                                                     f16* __restrict__ xblk) {
  __shared__ f16 tile[128 * 72];  // stride 72 breaks bank conflicts
  const int kb = blockIdx.x, mt = blockIdx.y, t = threadIdx.x;
  const float* xp = x + (size_t)mt * 128 * 768 + kb * 64;
#pragma unroll
  for (int it = 0; it < 8; ++it) {
    int idx = it * 256 + t;
    int row = idx >> 4, kc4 = (idx & 15) * 4;
    f32x4 v = *(const f32x4*)(xp + (size_t)row * 768 + kc4);
    f16x4 h;
    h[0] = (f16)v[0]; h[1] = (f16)v[1]; h[2] = (f16)v[2]; h[3] = (f16)v[3];
    *(f16x4*)(tile + row * 72 + kc4) = h;
  }
  __syncthreads();
  f16* op = xblk + (size_t)mt * 98304 + kb * 8192;
#pragma unroll
  for (int it = 0; it < 4; ++it) {
    int c = it * 256 + t;
    int kchunk = c >> 7, m = c & 127;
    f16x4 lo = *(const f16x4*)(tile + m * 72 + kchunk * 8);
    f16x4 hi = *(const f16x4*)(tile + m * 72 + kchunk * 8 + 4);
    *(f16x4*)(op + c * 8) = lo;
    *(f16x4*)(op + c * 8 + 4) = hi;
  }
}

// W (fp32, R x Cc, row-major) -> W^T f16 blocked at output-col offset col_off.
// grid (Cc/32, R/32), block 256.
__global__ __launch_bounds__(256) void transpose_w_kernel(const float* __restrict__ W,
                                                          f16* __restrict__ outblk,
                                                          int Cc, int col_off) {
  __shared__ float tile[32][33];
  const int c0 = blockIdx.x * 32, r0 = blockIdx.y * 32, t = threadIdx.x;
#pragma unroll
  for (int it = 0; it < 4; ++it) {
    int rr = it * 8 + (t >> 5), cc = t & 31;
    tile[rr][cc] = W[(size_t)(r0 + rr) * Cc + c0 + cc];
  }
  __syncthreads();
  if (t < 128) {
    int cl = t >> 2, rb = t & 3;
    int cg = col_off + c0 + cl;
    int rg = r0 + rb * 8;
    f16x4 v0, v1;
#pragma unroll
    for (int u = 0; u < 4; ++u) v0[u] = (f16)tile[rb * 8 + u][cl];
#pragma unroll
    for (int u = 0; u < 4; ++u) v1[u] = (f16)tile[rb * 8 + 4 + u][cl];
    size_t base = (size_t)(cg >> 7) * 98304 + (size_t)(rg >> 3) * 1024 +
                  (size_t)(cg & 127) * 8;
    *(f16x4*)(outblk + base) = v0;
    *(f16x4*)(outblk + base + 4) = v1;
  }
}

// ---------------------------------------------------------------------------
// Main GEMM. BM=128, BN=256, BK=32, 8 waves (2M x 4N), per-wave 64x64
// (acc 4x4). TRIPLE-buffered 72KB LDS -> 2 blocks/CU. 24 K-tiles; per tile:
//   STAGE(buf[j+2], j+2): 3x global_load_lds (A 8KB, B 2x8KB)
//   8x ds_read_b128 fragments from buf[j]
//   lgkmcnt(0); setprio(1) 16 MFMA setprio(0)
//   vmcnt(3); s_barrier   // j+1 landed; j+2 stays in flight
// Epilogue: values staged through the (now dead) 72KB LDS in the exact
// global blocked layout, then block-copied as full-cacheline f16x8/f32x4
// stores (kills read-for-ownership traffic of partial-line scatter).
// MODE 0: X@[Wqg|Wkv] (NN=3072), fused pola epilogue. grid (12, 256).
// MODE 1: pre@Wproj (NN=768), +bproj, FLOAT32 out.     grid (3, 256).
template <int MODE>
__global__ __launch_bounds__(512, 4) void gemm_kernel(
    const f16* __restrict__ Ablk, const f16* __restrict__ Bblk,
    const float* __restrict__ powr, const float* __restrict__ iscale,
    const float* __restrict__ pos_enc, const float* __restrict__ bproj,
    f16* __restrict__ qpow, f16* __restrict__ gbuf, f16* __restrict__ kpow,
    f16* __restrict__ vt, float* __restrict__ outp) {
  constexpr int A_SZ = 4096;             // f16: 128 rows x 32 k
  constexpr int STR  = 12288;            // f16 per buffer (A 8KB + B 16KB)
  __shared__ f16 smem[3 * STR];          // 72KB
  const int t = threadIdx.x;
  const int wid = t >> 6, lane = t & 63;
  const int c16 = lane & 15, q = lane >> 4;
  const int ntile = blockIdx.x, mtile = blockIdx.y;
  const int wm = wid >> 2, wn = wid & 3;       // 2M x 4N
  const int bh2 = wn >> 1, bc = (wn & 1) * 64; // B half / 64-col base
  const f16* Ap = Ablk + (size_t)mtile * 98304;
  const f16* Bp = Bblk + (size_t)ntile * 196608;

  auto STAGE = [&](int buf, int k0) {
    const size_t gk = (size_t)(k0 >> 3) * 1024;
    gload_lds16(Ap + gk + (size_t)t * 8, smem + buf * STR + wid * 512);
    gload_lds16(Bp + gk + (size_t)t * 8, smem + buf * STR + A_SZ + wid * 512);
    gload_lds16(Bp + 98304 + gk + (size_t)t * 8,
                smem + buf * STR + A_SZ + 4096 + wid * 512);
  };

  f32x4 acc[4][4];
#pragma unroll
  for (int i = 0; i < 4; ++i)
#pragma unroll
    for (int j = 0; j < 4; ++j) acc[i][j] = (f32x4){0.f, 0.f, 0.f, 0.f};

  STAGE(0, 0);
  STAGE(1, 32);
  asm volatile("s_waitcnt vmcnt(3)");  // tile0 resident; tile1 in flight
  __builtin_amdgcn_sched_barrier(0);
  __builtin_amdgcn_s_barrier();
  __builtin_amdgcn_sched_barrier(0);

  int cur = 0, nx2 = 2;
  for (int j = 0; j < 24; ++j) {
    if (j < 22) STAGE(nx2, (j + 2) * 32);
    const f16* A_ = smem + cur * STR;
    const f16* B_ = smem + cur * STR + A_SZ + bh2 * 4096;
    f16x8 af[4], bf[4];
    const int kc = q * 1024;
#pragma unroll
    for (int mi = 0; mi < 4; ++mi)
      af[mi] = *(const f16x8*)(A_ + kc + (wm * 64 + mi * 16 + c16) * 8);
#pragma unroll
    for (int ni = 0; ni < 4; ++ni)
      bf[ni] = *(const f16x8*)(B_ + kc + (bc + ni * 16 + c16) * 8);
    asm volatile("s_waitcnt lgkmcnt(0)");
    __builtin_amdgcn_sched_barrier(0);
    __builtin_amdgcn_s_setprio(1);
#pragma unroll
    for (int mi = 0; mi < 4; ++mi)
#pragma unroll
      for (int ni = 0; ni < 4; ++ni) mfma(acc[mi][ni], af[mi], bf[ni]);
    __builtin_amdgcn_s_setprio(0);
    __builtin_amdgcn_sched_barrier(0);
    if (j < 22)       asm volatile("s_waitcnt vmcnt(3)");
    else if (j == 22) asm volatile("s_waitcnt vmcnt(0)");
    __builtin_amdgcn_sched_barrier(0);
    __builtin_amdgcn_s_barrier();
    __builtin_amdgcn_sched_barrier(0);
    cur = (cur == 2) ? 0 : cur + 1;
    nx2 = (nx2 == 2) ? 0 : nx2 + 1;
  }
  // K-loop done; final barrier passed => smem is dead, reuse for epilogue.

  if (MODE == 0) {
    // 3072 output cols: 0..767 q, 768..1535 g, 1536..2303 k, 2304..3071 v
    const int sec = ntile / 3;
    const int csb = (ntile - sec * 3) * 256;
    const int h0 = csb >> 6;          // first of the 4 heads this block covers
    const int b = mtile >> 5;
    const int nim0 = (mtile & 31) * 128;
    f16* Es = smem;                   // 64KB staging in exact global layout

    if (sec == 0) {  // q^p -> 4 regions of 8192 f16: [bh][nim0>>7][d/8][m128][d%8]
#pragma unroll
      for (int ni = 0; ni < 4; ++ni) {
        const int dd = ni * 16 + c16;
        const int cs = csb + wn * 64 + dd;
        const float p = powr[cs], isc = iscale[cs];
        f16* eb = Es + wn * 8192 + (dd >> 3) * 1024 + (dd & 7);
#pragma unroll
        for (int mi = 0; mi < 4; ++mi) {
          const int m0 = wm * 64 + mi * 16 + q * 4;
#pragma unroll
          for (int r2 = 0; r2 < 4; ++r2) {
            float val = acc[mi][ni][r2] * isc;
            float av = fabsf(val);
            float e = (av > 0.f) ? exp2f(p * __log2f(av)) : 0.f;
            eb[(m0 + r2) * 8] = (f16)((val > 0.f) ? e : ((val < 0.f) ? -e : 0.f));
          }
        }
      }
      __syncthreads();
      const size_t ob = (size_t)(b * 12 + h0) * 262144 + (size_t)(nim0 >> 7) * 8192;
#pragma unroll
      for (int it = 0; it < 8; ++it) {
        int c = it * 512 + t;
        int r = c >> 10, i = (c & 1023) * 8;
        *(f16x8*)(qpow + ob + (size_t)r * 262144 + i) =
            *(const f16x8*)(Es + r * 8192 + i);
      }
    } else if (sec == 1) {  // g -> one 32768-f16 region of the blocked layout
#pragma unroll
      for (int ni = 0; ni < 4; ++ni) {
        const int colr = wn * 64 + ni * 16 + c16;  // 0..255
        f16* eb = Es + (colr >> 3) * 1024 + (colr & 7);
#pragma unroll
        for (int mi = 0; mi < 4; ++mi) {
          const int m0 = wm * 64 + mi * 16 + q * 4;
#pragma unroll
          for (int r2 = 0; r2 < 4; ++r2)
            eb[(m0 + r2) * 8] = (f16)acc[mi][ni][r2];
        }
      }
      __syncthreads();
      f16* gdst = gbuf + (size_t)(b * 32 + (nim0 >> 7)) * 98304 +
                  (size_t)(csb >> 3) * 1024;
#pragma unroll
      for (int it = 0; it < 8; ++it) {
        int c = it * 512 + t;
        *(f16x8*)(gdst + (size_t)c * 8) = *(const f16x8*)(Es + (size_t)c * 8);
      }
    } else if (sec == 2) {  // k^p -> 4 regions of 8192 f16: [bh][n/8][d][n%8]
#pragma unroll
      for (int ni = 0; ni < 4; ++ni) {
        const int dd = ni * 16 + c16;
        const int cs = csb + wn * 64 + dd;
        const float p = powr[cs], isc = iscale[cs];
#pragma unroll
        for (int mi = 0; mi < 4; ++mi) {
          const int nl = wm * 64 + mi * 16 + q * 4;  // 0..127
          f16x4 pk;
#pragma unroll
          for (int r2 = 0; r2 < 4; ++r2) {
            int n = nim0 + nl + r2;
            float val = (acc[mi][ni][r2] + pos_enc[(size_t)n * 768 + cs]) * isc;
            float av = fabsf(val);
            float e = (av > 0.f) ? exp2f(p * __log2f(av)) : 0.f;
            pk[r2] = (f16)((val > 0.f) ? e : ((val < 0.f) ? -e : 0.f));
          }
          *(f16x4*)(Es + wn * 8192 + (nl >> 3) * 512 + dd * 8 + (nl & 7)) = pk;
        }
      }
      __syncthreads();
      const size_t ob = (size_t)(b * 12 + h0) * 262144 + (size_t)(nim0 >> 3) * 512;
#pragma unroll
      for (int it = 0; it < 8; ++it) {
        int c = it * 512 + t;
        int r = c >> 10, i = (c & 1023) * 8;
        *(f16x8*)(kpow + ob + (size_t)r * 262144 + i) =
            *(const f16x8*)(Es + r * 8192 + i);
      }
    } else {  // v -> vT planes [bh*64+d][4096]: 256B full-line row segments
#pragma unroll
      for (int ni = 0; ni < 4; ++ni) {
        const int dd = ni * 16 + c16;
#pragma unroll
        for (int mi = 0; mi < 4; ++mi) {
          const int nl = wm * 64 + mi * 16 + q * 4;
          f16x4 vv4;
#pragma unroll
          for (int r2 = 0; r2 < 4; ++r2) vv4[r2] = (f16)acc[mi][ni][r2];
          *(f16x4*)(Es + wn * 8192 + dd * 128 + nl) = vv4;
        }
      }
      __syncthreads();
#pragma unroll
      for (int it = 0; it < 8; ++it) {
        int c = it * 512 + t;  // 4096 chunks: [r4][d64][nc16]
        int r = c >> 10, dd = (c >> 4) & 63, nc = (c & 15) * 8;
        *(f16x8*)(vt + (size_t)((b * 12 + h0 + r) * 64 + dd) * 4096 + nim0 + nc) =
            *(const f16x8*)(Es + r * 8192 + dd * 128 + nc);
      }
    }
  } else {
    // fp32 out, row-major. Stage 64-row halves (64KB) -> full-line f32x4.
    float* Ef = (float*)smem;
#pragma unroll
    for (int p = 0; p < 2; ++p) {
      if (wm == p) {
#pragma unroll
        for (int ni = 0; ni < 4; ++ni) {
          const int colr = wn * 64 + ni * 16 + c16;
          const float bb = bproj[ntile * 256 + colr];
#pragma unroll
          for (int mi = 0; mi < 4; ++mi) {
            const int row = mi * 16 + q * 4;
#pragma unroll
            for (int r2 = 0; r2 < 4; ++r2)
              Ef[(row + r2) * 256 + colr] = acc[mi][ni][r2] + bb;
          }
        }
      }
      __syncthreads();
#pragma unroll
      for (int it = 0; it < 8; ++it) {
        int c = it * 512 + t;  // 4096 f32x4 chunks: [row64][cc64]
        int row = c >> 6, cc = (c & 63) * 4;
        *(f32x4*)(outp + (size_t)(mtile * 128 + p * 64 + row) * 768 +
                  ntile * 256 + cc) = *(const f32x4*)(Ef + row * 256 + cc);
      }
      __syncthreads();
    }
  }
}

// OUT[vv][kk] = sum_n v[n][vv]*k_cat[n][kk], per (bh, split) over 1024 n.
// Fuses ksum (sum over n of k_cat columns) into the already-loaded k regs.
// grid (96, 4), block 256. Partials: kvp[bh][split][64][128],
// ksp[bh][split][128] (kk<64 = sum relu, kk>=64 = sum nrelu).
__global__ __launch_bounds__(256) void kv_kernel(const f16* __restrict__ kpow,
                                                 const f16* __restrict__ vt,
                                                 float* __restrict__ kvp,
                                                 float* __restrict__ ksp) {
  __shared__ f16 Ks[8192];  // [nchunk8][kk128][8]
  __shared__ f16 Vs[4096];  // [nchunk8][vv64 xor-swizzled][8]
  __shared__ float rp[256], rn[256];
  const int bh = blockIdx.x, split = blockIdx.y, t = threadIdx.x;
  const int wave = t >> 6, lane = t & 63;
  const int c16 = lane & 15, q = lane >> 4;
  const f16* kb = kpow + (size_t)bh * 262144;
  const f16* vb = vt + (size_t)bh * 64 * 4096;
  f32x4 acc[4][2];
#pragma unroll
  for (int i = 0; i < 4; ++i)
#pragma unroll
    for (int j = 0; j < 2; ++j) acc[i][j] = (f32x4){0.f, 0.f, 0.f, 0.f};
  float sp = 0.f, sn = 0.f;  // ksum partials, this thread's d = t&63

  const int n_beg = split * 1024, n_end = n_beg + 1024;
  for (int n0 = n_beg; n0 < n_end; n0 += 64) {
    f16x8 kr[2], vr[2];
#pragma unroll
    for (int r = 0; r < 2; ++r)
      kr[r] = *(const f16x8*)(kb + (size_t)n0 * 64 + (size_t)(r * 256 + t) * 8);
#pragma unroll
    for (int r = 0; r < 2; ++r) {
      int cc = r * 256 + t;
      int vv = cc >> 3, nc = cc & 7;
      vr[r] = *(const f16x8*)(vb + (size_t)vv * 4096 + n0 + nc * 8);
    }
    // fused ksum: each kr[r] is 8 consecutive n at column d = t&63
#pragma unroll
    for (int r = 0; r < 2; ++r)
#pragma unroll
      for (int u = 0; u < 8; ++u) {
        float f = (float)kr[r][u];
        sp += (f > 0.f) ? f : 0.f;
        sn += (f < 0.f) ? -f : 0.f;
      }
    __syncthreads();
#pragma unroll
    for (int r = 0; r < 2; ++r) {
      int cp = r * 256 + t;
      int nch = cp >> 6, d = cp & 63;
      *(f16x8*)(Ks + (size_t)(nch * 1024 + d * 8)) = relu8(kr[r]);
      *(f16x8*)(Ks + (size_t)(nch * 1024 + (d + 64) * 8)) = nrelu8(kr[r]);
    }
#pragma unroll
    for (int r = 0; r < 2; ++r) {
      int cc = r * 256 + t;
      int vv = cc >> 3, nc = cc & 7;
      *(f16x8*)(Vs + (size_t)(nc * 64 + (vv ^ nc)) * 8) = vr[r];
    }
    __syncthreads();
#pragma unroll
    for (int s = 0; s < 2; ++s) {
      f16x8 af[4], bf2[2];
#pragma unroll
      for (int i = 0; i < 4; ++i) {
        int m = i * 16 + c16, nc2 = s * 4 + q;
        af[i] = *(const f16x8*)(Vs + (nc2 * 64 + (m ^ nc2)) * 8);
      }
#pragma unroll
      for (int j = 0; j < 2; ++j)
        bf2[j] = *(const f16x8*)(Ks + ((s * 4 + q) * 128 + wave * 32 + j * 16 + c16) * 8);
#pragma unroll
      for (int i = 0; i < 4; ++i)
#pragma unroll
        for (int j = 0; j < 2; ++j) mfma(acc[i][j], af[i], bf2[j]);
    }
    __syncthreads();
  }
  float* kvb = kvp + (size_t)(bh * 4 + split) * 8192;
#pragma unroll
  for (int i = 0; i < 4; ++i)
#pragma unroll
    for (int j = 0; j < 2; ++j) {
      int kk = wave * 32 + j * 16 + c16;
      int vv0 = i * 16 + q * 4;
#pragma unroll
      for (int r2 = 0; r2 < 4; ++r2)
        kvb[(size_t)(vv0 + r2) * 128 + kk] = acc[i][j][r2];
    }
  rp[t] = sp; rn[t] = sn;
  __syncthreads();
  if (t < 64) {
    float* ko = ksp + (size_t)(bh * 4 + split) * 128;
    ko[t] = rp[t] + rp[t + 64] + rp[t + 128] + rp[t + 192];
    ko[64 + t] = rn[t] + rn[t + 64] + rn[t + 128] + rn[t + 192];
  }
}

// Build BxT[bh][80][128] f16 from the 4 split partials: xa-GEMM B-operand
// rows: x_sim cols 0..31, x_opp 32..63, denominators 64..65, zero pad 66..79.
// grid 96, block 128.
__global__ void bx_kernel(const float* __restrict__ kvp,
                          const float* __restrict__ ksp, f16* __restrict__ bxt) {
  const int bh = blockIdx.x, kk = threadIdx.x;
  const float inv_n = 1.f / 4096.f;
  const float* kv0 = kvp + (size_t)bh * 4 * 8192;
  const float* ks0 = ksp + (size_t)bh * 4 * 128;
  f16* ob = bxt + (size_t)bh * 80 * 128;
  for (int nn = 0; nn < 32; ++nn) {
    float v = kv0[nn * 128 + kk] + kv0[8192 + nn * 128 + kk] +
              kv0[16384 + nn * 128 + kk] + kv0[24576 + nn * 128 + kk];
    ob[nn * 128 + kk] = (f16)(v * inv_n);
  }
  const int kx = kk ^ 64;
  for (int nn = 32; nn < 64; ++nn) {
    float v = kv0[nn * 128 + kx] + kv0[8192 + nn * 128 + kx] +
              kv0[16384 + nn * 128 + kx] + kv0[24576 + nn * 128 + kx];
    ob[nn * 128 + kk] = (f16)(v * inv_n);
  }
  float s0 = ks0[kk] + ks0[128 + kk] + ks0[256 + kk] + ks0[384 + kk];
  ob[64 * 128 + kk] = (f16)(s0 * inv_n);
  float s1 = ks0[kx] + ks0[128 + kx] + ks0[256 + kx] + ks0[384 + kx];
  ob[65 * 128 + kk] = (f16)(s1 * inv_n);
  for (int nn = 66; nn < 80; ++nn) ob[nn * 128 + kk] = (f16)0.f;
}

// Depthwise 5x5 SAME conv on 64x64 images. grid 96*64.
__global__ __launch_bounds__(256) void conv_kernel(const f16* __restrict__ vt,
                                                   const float* __restrict__ w,
                                                   const float* __restrict__ bias,
                                                   f16* __restrict__ vpos) {
  __shared__ float img[68 * 69];
  const int blk = blockIdx.x;
  const int d = blk & 63, bh = blk >> 6;
  const f16* src = vt + (size_t)(bh * 64 + d) * 4096;
  // interior: vectorized f16x4 loads (64 cols = 16 quads per row)
  for (int i = threadIdx.x; i < 68 * 16; i += 256) {
    int yy = i >> 4, g4 = i & 15;
    int y = yy - 2;
    float v0 = 0.f, v1 = 0.f, v2 = 0.f, v3 = 0.f;
    if ((unsigned)y < 64u) {
      f16x4 v = *(const f16x4*)(src + y * 64 + g4 * 4);
      v0 = (float)v[0]; v1 = (float)v[1]; v2 = (float)v[2]; v3 = (float)v[3];
    }
    float* row = img + yy * 69 + 2 + g4 * 4;
    row[0] = v0; row[1] = v1; row[2] = v2; row[3] = v3;
  }
  // border cols x = -2,-1,64,65 -> zeros
  for (int i = threadIdx.x; i < 68 * 4; i += 256) {
    int yy = i >> 2, c = i & 3;
    int xx = (c < 2) ? c : 64 + c;  // 0,1,66,67
    img[yy * 69 + xx] = 0.f;
  }
  float wr[25];
#pragma unroll
  for (int k = 0; k < 25; ++k) wr[k] = w[d * 25 + k];
  const float bb = bias[d];
  __syncthreads();
  f16* dst = vpos + (size_t)(bh * 64 + d) * 4096;
  for (int g4 = threadIdx.x; g4 < 1024; g4 += 256) {
    int y = g4 >> 4, x4 = (g4 & 15) * 4;
    float o0 = bb, o1 = bb, o2 = bb, o3 = bb;
#pragma unroll
    for (int ky = 0; ky < 5; ++ky) {
      const float* row = img + (y + ky) * 69 + x4;
      float r[8];
#pragma unroll
      for (int u = 0; u < 8; ++u) r[u] = row[u];
#pragma unroll
      for (int kx = 0; kx < 5; ++kx) {
        float wv = wr[ky * 5 + kx];
        o0 += r[kx] * wv;
        o1 += r[kx + 1] * wv;
        o2 += r[kx + 2] * wv;
        o3 += r[kx + 3] * wv;
      }
    }
    f16x4 st;
    st[0] = (f16)o0; st[1] = (f16)o1; st[2] = (f16)o2; st[3] = (f16)o3;
    *(f16x4*)(dst + y * 64 + x4) = st;
  }
}

// xa = q_sim @ Bx (4096x80x128 per bh), z-normalize, add v_pos, gate by g,
// write `pre` blocked for the projection GEMM. grid (32, 96), block 256.
// vpos tile staged via Ps; gbuf tile and the output tile staged through the
// dead Qs buffer -> all global IO is coalesced b128.
__global__ __launch_bounds__(256) void xa_kernel(
    const f16* __restrict__ qpow, const f16* __restrict__ bxt,
    const f16* __restrict__ vpos, const f16* __restrict__ gbuf,
    f16* __restrict__ pre) {
  __shared__ f16 Qs[16384];     // q_sim tile; after MFMA: [0:8192)=G, [8192:16384)=OUT
  __shared__ f16 Ps[64 * 134];  // vpos tile [col][n], stride 134 vs banks
  __shared__ float zs[256];
  const int nb = blockIdx.x, bh = blockIdx.y;
  const int b = bh / 12, h = bh % 12;
  const int t = threadIdx.x;
  const int wave = t >> 6, lane = t & 63;
  const int c16 = lane & 15, q = lane >> 4;
  const f16* qb = qpow + (size_t)bh * 262144 + (size_t)nb * 8192;
  // blocked-tile base shared by gbuf and pre: tok0 = b*4096+nb*128, kchunks h*8..
  const size_t gp2 = (size_t)(b * 32 + nb) * 98304 + (size_t)(h * 8) * 1024;
  f16x8 qr[4], gr[4];
#pragma unroll
  for (int r = 0; r < 4; ++r)
    qr[r] = *(const f16x8*)(qb + (size_t)(r * 256 + t) * 8);
#pragma unroll
  for (int r = 0; r < 4; ++r)
    gr[r] = *(const f16x8*)(gbuf + gp2 + (size_t)(r * 256 + t) * 8);
#pragma unroll
  for (int r = 0; r < 4; ++r) {
    int c = r * 256 + t;
    int dch = c >> 7, row = c & 127;
    *(f16x8*)(Qs + (size_t)(dch * 1024 + row * 8)) = relu8(qr[r]);
    *(f16x8*)(Qs + (size_t)((dch + 8) * 1024 + row * 8)) = nrelu8(qr[r]);
  }
  // stage vpos[bh][col][nb*128 .. +128] -> Ps[col][n], coalesced 16B loads
  {
    const f16* vpb = vpos + (size_t)bh * 262144 + (size_t)nb * 128;
#pragma unroll
    for (int it = 0; it < 4; ++it) {
      int idx = it * 256 + t;          // 1024 chunks of 8 f16
      int col = idx >> 4, nc = idx & 15;
      f16x8 v = *(const f16x8*)(vpb + (size_t)col * 4096 + nc * 8);
      *(f16x8*)(Ps + col * 134 + nc * 8) = v;
    }
  }
  __syncthreads();
  f32x4 acc[2][5];
#pragma unroll
  for (int i = 0; i < 2; ++i)
#pragma unroll
    for (int j = 0; j < 5; ++j) acc[i][j] = (f32x4){0.f, 0.f, 0.f, 0.f};
  const f16* bx = bxt + (size_t)bh * 80 * 128;
#pragma unroll
  for (int s = 0; s < 4; ++s) {
    f16x8 af[2], bf5[5];
#pragma unroll
    for (int i = 0; i < 2; ++i)
      af[i] = *(const f16x8*)(Qs + ((s * 4 + q) * 1024 + (wave * 32 + i * 16 + c16) * 8));
#pragma unroll
    for (int j = 0; j < 5; ++j)
      bf5[j] = *(const f16x8*)(bx + (size_t)(j * 16 + c16) * 128 + s * 32 + q * 8);
#pragma unroll
    for (int i = 0; i < 2; ++i)
#pragma unroll
      for (int j = 0; j < 5; ++j) mfma(acc[i][j], af[i], bf5[j]);
  }
  // denominators: tile col 4 -> col 64 (sim) at c16==0, col 65 (opp) at c16==1
  if (c16 < 2) {
#pragma unroll
    for (int i = 0; i < 2; ++i) {
      int mloc = wave * 32 + i * 16 + q * 4;
#pragma unroll
      for (int r2 = 0; r2 < 4; ++r2) zs[(mloc + r2) * 2 + c16] = acc[i][4][r2];
    }
  }
  __syncthreads();  // all waves done with Qs -> reuse as G / OUT staging
  f16* Gs = Qs;          // [kc8][m128][dd8] linear = global blocked layout
  f16* Os = Qs + 8192;
#pragma unroll
  for (int r = 0; r < 4; ++r)
    *(f16x8*)(Gs + (size_t)(r * 256 + t) * 8) = gr[r];
  __syncthreads();
#pragma unroll
  for (int i = 0; i < 2; ++i) {
    const int mbase = wave * 32 + i * 16 + q * 4;
#pragma unroll
    for (int j = 0; j < 4; ++j) {
      const int col = j * 16 + c16;  // 0..63
      const int zsel = col >> 5;
      const int gidx = (col >> 3) * 1024 + (col & 7);
#pragma unroll
      for (int r2 = 0; r2 < 4; ++r2) {
        const int mloc = mbase + r2;
        const float den = zs[mloc * 2 + zsel];
        const float xav = acc[i][j][r2] / (den + 1e-6f);
        const float vp = (float)Ps[col * 134 + mloc];
        const float gg = (float)Gs[gidx + mloc * 8];
        Os[gidx + mloc * 8] = (f16)((xav + vp) * gg);
      }
    }
  }
  __syncthreads();
#pragma unroll
  for (int r = 0; r < 4; ++r)
    *(f16x8*)(pre + gp2 + (size_t)(r * 256 + t) * 8) =
        *(const f16x8*)(Os + (size_t)(r * 256 + t) * 8);
}

// ---------------------------------------------------------------------------
extern "C" void kernel_launch(void* const* d_in, const int* in_sizes, int n_in,
                              void* d_out, int out_size, void* d_ws, size_t ws_size,
                              hipStream_t stream) {
  const float* x       = (const float*)d_in[0];
  const float* Wqg     = (const float*)d_in[1];
  const float* Wkv     = (const float*)d_in[2];
  const float* Wproj   = (const float*)d_in[3];
  const float* bproj   = (const float*)d_in[4];
  const float* dwc_w   = (const float*)d_in[5];
  const float* dwc_b   = (const float*)d_in[6];
  const float* power_p = (const float*)d_in[7];
  const float* scale_p = (const float*)d_in[8];
  const float* pos_enc = (const float*)d_in[9];
  float* outp = (float*)d_out;  // FLOAT32 output (reference output dtype)

  char* ws = (char*)d_ws;
  // Workspace layout (bytes). Total ~247.6 MiB.
  constexpr size_t o_qpow = 0;          // 50331648  signed q^p
  constexpr size_t o_kpow = 50331648;   // 50331648  signed k^p (later: vpos)
  constexpr size_t o_vt   = 100663296;  // 50331648  v transposed planes
  constexpr size_t o_gbuf = 150994944;  // 50331648  gate, blocked layout
  constexpr size_t o_xblk = 201326592;  // 50331648  x blocked (later: kvp/ksp, then pre)
  constexpr size_t o_wta  = 251658240;  // 4718592   [Wqg|Wkv]^T
  constexpr size_t o_wtp  = 256376832;  // 1179648   Wproj^T
  constexpr size_t o_isc  = 257556480;  // 3072+pad
  constexpr size_t o_pwr  = 257560576;  // 3072+pad
  constexpr size_t o_bxt  = 257564672;  // 1966080

  f16*   qpow = (f16*)(ws + o_qpow);
  f16*   kpow = (f16*)(ws + o_kpow);
  f16*   vt   = (f16*)(ws + o_vt);
  f16*   gbuf = (f16*)(ws + o_gbuf);
  f16*   xblk = (f16*)(ws + o_xblk);
  f16*   wta  = (f16*)(ws + o_wta);
  f16*   wtp  = (f16*)(ws + o_wtp);
  float* isc  = (float*)(ws + o_isc);
  float* pwr  = (float*)(ws + o_pwr);
  f16*   bxt  = (f16*)(ws + o_bxt);
  // Aliases (stream-ordered lifetimes):
  //   xblk (gemm<0> input) dies after gemm<0>; kvp/ksp live there until bx;
  //   then xa writes pre over the same region. kpow dies after kv -> vpos.
  float* kvp  = (float*)(ws + o_xblk);              // 96*4*8192*4 = 12.6 MB
  float* ksp  = (float*)(ws + o_xblk + 12582912);   // 96*4*128*4  = 0.2 MB
  f16*   vpos = kpow;
  f16*   pre  = xblk;

  prep_scalars_kernel<<<dim3(3), 256, 0, stream>>>(scale_p, power_p, isc, pwr);
  cast_x_kernel<<<dim3(12, 256), 256, 0, stream>>>(x, xblk);
  transpose_w_kernel<<<dim3(48, 24), 256, 0, stream>>>(Wqg, wta, 1536, 0);
  transpose_w_kernel<<<dim3(48, 24), 256, 0, stream>>>(Wkv, wta, 1536, 1536);
  transpose_w_kernel<<<dim3(24, 24), 256, 0, stream>>>(Wproj, wtp, 768, 0);
  gemm_kernel<0><<<dim3(12, 256), 512, 0, stream>>>(
      xblk, wta, pwr, isc, pos_enc, nullptr, qpow, gbuf, kpow, vt, nullptr);
  kv_kernel<<<dim3(96, 4), 256, 0, stream>>>(kpow, vt, kvp, ksp);
  bx_kernel<<<96, 128, 0, stream>>>(kvp, ksp, bxt);
  conv_kernel<<<6144, 256, 0, stream>>>(vt, dwc_w, dwc_b, vpos);
  xa_kernel<<<dim3(32, 96), 256, 0, stream>>>(qpow, bxt, vpos, gbuf, pre);
  gemm_kernel<1><<<dim3(3, 256), 512, 0, stream>>>(
      pre, wtp, nullptr, nullptr, nullptr, bproj, nullptr, nullptr, nullptr,
      nullptr, outp);
}